// Round 1
// baseline (349.163 us; speedup 1.0000x reference)
//
#include <hip/hip_runtime.h>

#define D_DIM 1024
#define NROWS 8192

typedef __bf16 bf16x8 __attribute__((ext_vector_type(8)));
typedef float f32x4 __attribute__((ext_vector_type(4)));

typedef const __attribute__((address_space(1))) void* gaddr_t;
typedef __attribute__((address_space(3))) void* laddr_t;

__device__ __forceinline__ void load16_to_lds(const void* g, void* l) {
    __builtin_amdgcn_global_load_lds((gaddr_t)g, (laddr_t)l, 16, 0, 0);
}

__device__ __forceinline__ unsigned short f2bf(float f) {
    unsigned int u = __float_as_uint(f);
    u += 0x7FFFu + ((u >> 16) & 1u);   // round-to-nearest-even (finite inputs only)
    return (unsigned short)(u >> 16);
}

// ---- kernel 0: zero the encoded max arrays (ws is poisoned 0xAA each call)
__global__ void init_max(int* __restrict__ p, int n) {
    int i = blockIdx.x * blockDim.x + threadIdx.x;
    if (i < n) p[i] = 0;   // 0 < int-encoding of any (cosine+2.0) > 0
}

// ---- kernel 1: fp32 row-normalize -> bf16 row-major (8192x1024 each)
__global__ __launch_bounds__(256) void normalize_rows(const float* __restrict__ ex,
                                                      const float* __restrict__ ey,
                                                      unsigned short* __restrict__ Abf,
                                                      unsigned short* __restrict__ Bbf) {
    int r = blockIdx.x;
    const float* src;
    unsigned short* dst;
    if (r < NROWS) { src = ex + (size_t)r * D_DIM;         dst = Abf + (size_t)r * D_DIM; }
    else           { src = ey + (size_t)(r - NROWS) * D_DIM; dst = Bbf + (size_t)(r - NROWS) * D_DIM; }

    int t = threadIdx.x;
    float4 v = ((const float4*)src)[t];
    float ss = v.x * v.x + v.y * v.y + v.z * v.z + v.w * v.w;
    #pragma unroll
    for (int off = 32; off; off >>= 1) ss += __shfl_xor(ss, off, 64);

    __shared__ float wsum[4];
    int wave = t >> 6, lane = t & 63;
    if (lane == 0) wsum[wave] = ss;
    __syncthreads();
    float tot = wsum[0] + wsum[1] + wsum[2] + wsum[3];
    float scale = 1.0f / fmaxf(sqrtf(tot), 1e-8f);

    ushort4 o;
    o.x = f2bf(v.x * scale);
    o.y = f2bf(v.y * scale);
    o.z = f2bf(v.z * scale);
    o.w = f2bf(v.w * scale);
    ((ushort4*)dst)[t] = o;
}

// ---- kernel 2: 128x128-tile bf16 MFMA GEMM (C = A . B^T) with fused row/col max
// A, B row-major [8192][1024] bf16. Never materializes C.
__global__ __launch_bounds__(256) void gemm_max(const unsigned short* __restrict__ A,
                                                const unsigned short* __restrict__ B,
                                                int* __restrict__ rowmax,
                                                int* __restrict__ colmax) {
    __shared__ __align__(16) unsigned short Alds[128 * 64];   // 16 KB, row stride 64 bf16
    __shared__ __align__(16) unsigned short Blds[128 * 64];   // 16 KB

    const int bm = blockIdx.x >> 6;
    const int bn = blockIdx.x & 63;
    const int rowb = bm * 128;
    const int colb = bn * 128;

    const int t    = threadIdx.x;
    const int lane = t & 63;
    const int wave = t >> 6;
    const int wm = (wave & 1) * 64;       // wave row offset within tile
    const int wn = (wave >> 1) * 64;      // wave col offset within tile
    const int fr = lane & 15;             // fragment row/col index
    const int fq = lane >> 4;             // quarter (0..3)
    const int fk = fq * 8;                // fragment k offset

    // staging map: thread t loads rows (t>>3)+32*i, 16B chunk (t&7)
    const int srow = t >> 3;
    const int scol = (t & 7) * 8;

    const unsigned short* Ag = A + (size_t)(rowb + srow) * D_DIM + scol;
    const unsigned short* Bg = B + (size_t)(colb + srow) * D_DIM + scol;

    f32x4 acc[4][4] = {};

    for (int kt = 0; kt < D_DIM; kt += 64) {
        #pragma unroll
        for (int i = 0; i < 4; ++i)
            load16_to_lds(Ag + (size_t)i * 32 * D_DIM + kt,
                          (char*)Alds + i * 4096 + wave * 1024);
        #pragma unroll
        for (int i = 0; i < 4; ++i)
            load16_to_lds(Bg + (size_t)i * 32 * D_DIM + kt,
                          (char*)Blds + i * 4096 + wave * 1024);
        __syncthreads();   // drains vmcnt(0) before barrier (compiler-inserted)

        #pragma unroll
        for (int kk = 0; kk < 64; kk += 32) {
            bf16x8 af[4], bf[4];
            #pragma unroll
            for (int i = 0; i < 4; ++i)
                af[i] = *(const bf16x8*)(Alds + (wm + i * 16 + fr) * 64 + kk + fk);
            #pragma unroll
            for (int j = 0; j < 4; ++j)
                bf[j] = *(const bf16x8*)(Blds + (wn + j * 16 + fr) * 64 + kk + fk);
            #pragma unroll
            for (int i = 0; i < 4; ++i)
                #pragma unroll
                for (int j = 0; j < 4; ++j)
                    acc[i][j] = __builtin_amdgcn_mfma_f32_16x16x32_bf16(af[i], bf[j], acc[i][j], 0, 0, 0);
        }
        __syncthreads();
    }

    // ---- epilogue: fused max reductions.
    // C/D layout (m89-verified): col = lane&15 (fr), row = fq*4 + reg.
    // acc[i][j] reg r -> global row = rowb+wm+i*16+fq*4+r, col = colb+wn+j*16+fr.
    const float SH = 2.0f;   // cosine >= -1 -> v+2 > 0 -> int-ordered float bits

    #pragma unroll
    for (int i = 0; i < 4; ++i) {
        #pragma unroll
        for (int r = 0; r < 4; ++r) {
            float m = fmaxf(fmaxf(acc[i][0][r], acc[i][1][r]),
                            fmaxf(acc[i][2][r], acc[i][3][r]));
            m = fmaxf(m, __shfl_xor(m, 1, 64));   // reduce over the 16 lanes sharing fq
            m = fmaxf(m, __shfl_xor(m, 2, 64));
            m = fmaxf(m, __shfl_xor(m, 4, 64));
            m = fmaxf(m, __shfl_xor(m, 8, 64));
            if (fr == 0) {
                int row = rowb + wm + i * 16 + fq * 4 + r;
                atomicMax(&rowmax[row], __float_as_int(m + SH));
            }
        }
    }
    #pragma unroll
    for (int j = 0; j < 4; ++j) {
        float m = -1e30f;
        #pragma unroll
        for (int i = 0; i < 4; ++i)
            #pragma unroll
            for (int r = 0; r < 4; ++r)
                m = fmaxf(m, acc[i][j][r]);
        m = fmaxf(m, __shfl_xor(m, 16, 64));      // reduce over the 4 quarters
        m = fmaxf(m, __shfl_xor(m, 32, 64));
        if (fq == 0) {
            int col = colb + wn + j * 16 + fr;
            atomicMax(&colmax[col], __float_as_int(m + SH));
        }
    }
}

// ---- kernel 3: decode maxes, log-prob, sum. block 0 -> C1 (rowmax), block 1 -> C2 (colmax)
__global__ __launch_bounds__(256) void finalize(const int* __restrict__ rowmax,
                                                const int* __restrict__ colmax,
                                                float* __restrict__ out) {
    const int* src = (blockIdx.x == 0) ? rowmax : colmax;
    int t = threadIdx.x;
    float s = 0.0f;
    for (int i = t; i < NROWS; i += 256) {
        float v = __int_as_float(src[i]) - 2.0f;
        float z = (v - 1.0f) * (1.0f / 0.3f);
        s += -0.5f * z * z + 0.2850342711212634f;   // -(log(0.3)+0.5*log(2*pi))
    }
    #pragma unroll
    for (int off = 32; off; off >>= 1) s += __shfl_xor(s, off, 64);
    __shared__ float wsum[4];
    if ((t & 63) == 0) wsum[t >> 6] = s;
    __syncthreads();
    if (t == 0) out[blockIdx.x] = wsum[0] + wsum[1] + wsum[2] + wsum[3];
}

extern "C" void kernel_launch(void* const* d_in, const int* in_sizes, int n_in,
                              void* d_out, int out_size, void* d_ws, size_t ws_size,
                              hipStream_t stream) {
    const float* ex = (const float*)d_in[0];
    const float* ey = (const float*)d_in[1];
    float* out = (float*)d_out;

    char* ws = (char*)d_ws;
    unsigned short* Abf = (unsigned short*)ws;                                  // 16 MB
    unsigned short* Bbf = (unsigned short*)(ws + (size_t)NROWS * D_DIM * 2);    // 16 MB
    int* rowmax = (int*)(ws + (size_t)2 * NROWS * D_DIM * 2);                   // 32 KB
    int* colmax = rowmax + NROWS;                                               // 32 KB

    init_max<<<(2 * NROWS + 255) / 256, 256, 0, stream>>>(rowmax, 2 * NROWS);
    normalize_rows<<<2 * NROWS, 256, 0, stream>>>(ex, ey, Abf, Bbf);
    gemm_max<<<64 * 64, 256, 0, stream>>>(Abf, Bbf, rowmax, colmax);
    finalize<<<2, 256, 0, stream>>>(rowmax, colmax, out);
}

// Round 2
// 298.873 us; speedup vs baseline: 1.1683x; 1.1683x over previous
//
#include <hip/hip_runtime.h>

#define D_DIM 1024
#define NROWS 8192

typedef __bf16 bf16x8 __attribute__((ext_vector_type(8)));
typedef float f32x4 __attribute__((ext_vector_type(4)));

typedef const __attribute__((address_space(1))) void* gaddr_t;
typedef __attribute__((address_space(3))) void* laddr_t;

__device__ __forceinline__ void load16_to_lds(const void* g, void* l) {
    __builtin_amdgcn_global_load_lds((gaddr_t)g, (laddr_t)l, 16, 0, 0);
}

__device__ __forceinline__ unsigned short f2bf(float f) {
    unsigned int u = __float_as_uint(f);
    u += 0x7FFFu + ((u >> 16) & 1u);   // round-to-nearest-even (finite inputs only)
    return (unsigned short)(u >> 16);
}

// ---- kernel 1: fp32 row-normalize -> bf16 row-major (8192x1024 each).
// Also zeroes the encoded-max array (one int per block) — ws is poisoned 0xAA.
__global__ __launch_bounds__(256) void normalize_rows(const float* __restrict__ ex,
                                                      const float* __restrict__ ey,
                                                      unsigned short* __restrict__ Abf,
                                                      unsigned short* __restrict__ Bbf,
                                                      int* __restrict__ maxenc) {
    int r = blockIdx.x;
    if (threadIdx.x == 0) maxenc[r] = 0;   // 0 < int-encoding of any (cosine+2.0) > 0

    const float* src;
    unsigned short* dst;
    if (r < NROWS) { src = ex + (size_t)r * D_DIM;           dst = Abf + (size_t)r * D_DIM; }
    else           { src = ey + (size_t)(r - NROWS) * D_DIM; dst = Bbf + (size_t)(r - NROWS) * D_DIM; }

    int t = threadIdx.x;
    float4 v = ((const float4*)src)[t];
    float ss = v.x * v.x + v.y * v.y + v.z * v.z + v.w * v.w;
    #pragma unroll
    for (int off = 32; off; off >>= 1) ss += __shfl_xor(ss, off, 64);

    __shared__ float wsum[4];
    int wave = t >> 6, lane = t & 63;
    if (lane == 0) wsum[wave] = ss;
    __syncthreads();
    float tot = wsum[0] + wsum[1] + wsum[2] + wsum[3];
    float scale = 1.0f / fmaxf(sqrtf(tot), 1e-8f);

    ushort4 o;
    o.x = f2bf(v.x * scale);
    o.y = f2bf(v.y * scale);
    o.z = f2bf(v.z * scale);
    o.w = f2bf(v.w * scale);
    ((ushort4*)dst)[t] = o;
}

// ---- kernel 2: 128x128-tile bf16 MFMA GEMM (C = A . B^T) with fused row/col max.
// LDS layout XOR-swizzled: 128-B row = 8 chunks of 16 B; chunk c of row r lives at
// position c ^ (r & 7). Fragment reads then hit 8 distinct bank groups (2 lanes each
// — free on wave64) instead of one group 16-way. The swizzle is applied on the
// global SOURCE address of each staging lane (global_load_lds dest is fixed at
// wave-base + lane*16), so data lands pre-swizzled.
__global__ __launch_bounds__(256) void gemm_max(const unsigned short* __restrict__ A,
                                                const unsigned short* __restrict__ B,
                                                int* __restrict__ rowmax,
                                                int* __restrict__ colmax) {
    __shared__ __align__(16) unsigned short Alds[128 * 64];   // 16 KB, row stride 64 bf16
    __shared__ __align__(16) unsigned short Blds[128 * 64];   // 16 KB

    const int bm = blockIdx.x >> 6;
    const int bn = blockIdx.x & 63;
    const int rowb = bm * 128;
    const int colb = bn * 128;

    const int t    = threadIdx.x;
    const int lane = t & 63;
    const int wave = t >> 6;
    const int wm = (wave & 1) * 64;       // wave row offset within tile
    const int wn = (wave >> 1) * 64;      // wave col offset within tile
    const int fr = lane & 15;             // fragment row/col index
    const int fq = lane >> 4;             // quarter (0..3)
    const int fsw = fr & 7;               // row-derived swizzle key for reads

    // staging map: thread t stages LDS row (t>>3), LDS chunk (t&7); with the XOR
    // swizzle that position holds GLOBAL chunk (t&7)^(row&7).
    const int srow = t >> 3;
    const int scol = ((t ^ (t >> 3)) & 7) * 8;

    const unsigned short* Ag = A + (size_t)(rowb + srow) * D_DIM + scol;
    const unsigned short* Bg = B + (size_t)(colb + srow) * D_DIM + scol;

    f32x4 acc[4][4] = {};

    for (int kt = 0; kt < D_DIM; kt += 64) {
        #pragma unroll
        for (int i = 0; i < 4; ++i)
            load16_to_lds(Ag + (size_t)i * 32 * D_DIM + kt,
                          (char*)Alds + i * 4096 + wave * 1024);
        #pragma unroll
        for (int i = 0; i < 4; ++i)
            load16_to_lds(Bg + (size_t)i * 32 * D_DIM + kt,
                          (char*)Blds + i * 4096 + wave * 1024);
        __syncthreads();

        #pragma unroll
        for (int kk = 0; kk < 64; kk += 32) {
            const int sc = (((kk >> 3) + fq) ^ fsw) * 8;   // swizzled chunk, in elements
            bf16x8 af[4], bfr[4];
            #pragma unroll
            for (int i = 0; i < 4; ++i)
                af[i] = *(const bf16x8*)(Alds + (wm + i * 16 + fr) * 64 + sc);
            #pragma unroll
            for (int j = 0; j < 4; ++j)
                bfr[j] = *(const bf16x8*)(Blds + (wn + j * 16 + fr) * 64 + sc);
            #pragma unroll
            for (int i = 0; i < 4; ++i)
                #pragma unroll
                for (int j = 0; j < 4; ++j)
                    acc[i][j] = __builtin_amdgcn_mfma_f32_16x16x32_bf16(af[i], bfr[j], acc[i][j], 0, 0, 0);
        }
        __syncthreads();
    }

    // ---- epilogue: fused max reductions.
    // C/D layout (m89-verified): col = lane&15 (fr), row = fq*4 + reg.
    const float SH = 2.0f;   // cosine >= -1 -> v+2 > 0 -> int-ordered float bits

    #pragma unroll
    for (int i = 0; i < 4; ++i) {
        #pragma unroll
        for (int r = 0; r < 4; ++r) {
            float m = fmaxf(fmaxf(acc[i][0][r], acc[i][1][r]),
                            fmaxf(acc[i][2][r], acc[i][3][r]));
            m = fmaxf(m, __shfl_xor(m, 1, 64));   // reduce over the 16 lanes sharing fq
            m = fmaxf(m, __shfl_xor(m, 2, 64));
            m = fmaxf(m, __shfl_xor(m, 4, 64));
            m = fmaxf(m, __shfl_xor(m, 8, 64));
            if (fr == 0) {
                int row = rowb + wm + i * 16 + fq * 4 + r;
                atomicMax(&rowmax[row], __float_as_int(m + SH));
            }
        }
    }
    #pragma unroll
    for (int j = 0; j < 4; ++j) {
        float m = -1e30f;
        #pragma unroll
        for (int i = 0; i < 4; ++i)
            #pragma unroll
            for (int r = 0; r < 4; ++r)
                m = fmaxf(m, acc[i][j][r]);
        m = fmaxf(m, __shfl_xor(m, 16, 64));      // reduce over the 4 quarters
        m = fmaxf(m, __shfl_xor(m, 32, 64));
        if (fq == 0) {
            int col = colb + wn + j * 16 + fr;
            atomicMax(&colmax[col], __float_as_int(m + SH));
        }
    }
}

// ---- kernel 3: decode maxes, log-prob, sum. block 0 -> C1 (rowmax), block 1 -> C2 (colmax)
__global__ __launch_bounds__(256) void finalize(const int* __restrict__ rowmax,
                                                const int* __restrict__ colmax,
                                                float* __restrict__ out) {
    const int* src = (blockIdx.x == 0) ? rowmax : colmax;
    int t = threadIdx.x;
    float s = 0.0f;
    for (int i = t; i < NROWS; i += 256) {
        float v = __int_as_float(src[i]) - 2.0f;
        float z = (v - 1.0f) * (1.0f / 0.3f);
        s += -0.5f * z * z + 0.2850342711212634f;   // -(log(0.3)+0.5*log(2*pi))
    }
    #pragma unroll
    for (int off = 32; off; off >>= 1) s += __shfl_xor(s, off, 64);
    __shared__ float wsum[4];
    if ((t & 63) == 0) wsum[t >> 6] = s;
    __syncthreads();
    if (t == 0) out[blockIdx.x] = wsum[0] + wsum[1] + wsum[2] + wsum[3];
}

extern "C" void kernel_launch(void* const* d_in, const int* in_sizes, int n_in,
                              void* d_out, int out_size, void* d_ws, size_t ws_size,
                              hipStream_t stream) {
    const float* ex = (const float*)d_in[0];
    const float* ey = (const float*)d_in[1];
    float* out = (float*)d_out;

    char* ws = (char*)d_ws;
    unsigned short* Abf = (unsigned short*)ws;                                  // 16 MB
    unsigned short* Bbf = (unsigned short*)(ws + (size_t)NROWS * D_DIM * 2);    // 16 MB
    int* rowmax = (int*)(ws + (size_t)2 * NROWS * D_DIM * 2);                   // 32 KB
    int* colmax = rowmax + NROWS;                                               // 32 KB

    normalize_rows<<<2 * NROWS, 256, 0, stream>>>(ex, ey, Abf, Bbf, rowmax);
    gemm_max<<<64 * 64, 256, 0, stream>>>(Abf, Bbf, rowmax, colmax);
    finalize<<<2, 256, 0, stream>>>(rowmax, colmax, out);
}

// Round 3
// 228.934 us; speedup vs baseline: 1.5252x; 1.3055x over previous
//
#include <hip/hip_runtime.h>

#define D_DIM 1024
#define NROWS 8192

typedef float f32x4 __attribute__((ext_vector_type(4)));

typedef const __attribute__((address_space(1))) void* gaddr_t;
typedef __attribute__((address_space(3))) void* laddr_t;

__device__ __forceinline__ void load16_to_lds(const void* g, void* l) {
    __builtin_amdgcn_global_load_lds((gaddr_t)g, (laddr_t)l, 16, 0, 0);
}

// ---- kernel 1: fp32 row-normalize -> fp8 e4m3 (OCP, HW-native on gfx950).
// Also zeroes the encoded-max array (one int per block) — ws is poisoned 0xAA.
__global__ __launch_bounds__(256) void normalize_rows(const float* __restrict__ ex,
                                                      const float* __restrict__ ey,
                                                      unsigned char* __restrict__ Aq,
                                                      unsigned char* __restrict__ Bq,
                                                      int* __restrict__ maxenc) {
    int r = blockIdx.x;
    if (threadIdx.x == 0) maxenc[r] = 0;   // 0 < int-encoding of any (cosine+2.0) > 0

    const float* src;
    unsigned char* dst;
    if (r < NROWS) { src = ex + (size_t)r * D_DIM;           dst = Aq + (size_t)r * D_DIM; }
    else           { src = ey + (size_t)(r - NROWS) * D_DIM; dst = Bq + (size_t)(r - NROWS) * D_DIM; }

    int t = threadIdx.x;
    float4 v = ((const float4*)src)[t];
    float ss = v.x * v.x + v.y * v.y + v.z * v.z + v.w * v.w;
    #pragma unroll
    for (int off = 32; off; off >>= 1) ss += __shfl_xor(ss, off, 64);

    __shared__ float wsum[4];
    int wave = t >> 6, lane = t & 63;
    if (lane == 0) wsum[wave] = ss;
    __syncthreads();
    float tot = wsum[0] + wsum[1] + wsum[2] + wsum[3];
    float scale = 1.0f / fmaxf(sqrtf(tot), 1e-8f);

    // v_cvt_pk_fp8_f32: RNE, saturating; values are |x| <= ~0.2 so no overflow.
    int packed = 0;
    packed = __builtin_amdgcn_cvt_pk_fp8_f32(v.x * scale, v.y * scale, packed, false);
    packed = __builtin_amdgcn_cvt_pk_fp8_f32(v.z * scale, v.w * scale, packed, true);
    ((int*)dst)[t] = packed;
}

// ---- kernel 2: 128x128-tile fp8 MFMA GEMM (C = A . B^T) with fused row/col max.
// BK=128 (fp8: 128 B/row, 32 KB LDS total — same footprint as the bf16 BK=64
// version, but half the K-iterations => half the barrier drains).
// LDS rows XOR-swizzled at 16-B-chunk granularity: chunk c of row r lives at
// c ^ (r&7); applied on the global SOURCE address of each staging lane
// (global_load_lds dest is fixed at wave-base + lane*16). Fragment b64 reads
// land at the width-minimum 4 lanes/bank (conflict-free for 8-B access).
__global__ __launch_bounds__(256) void gemm_max(const unsigned char* __restrict__ A,
                                                const unsigned char* __restrict__ B,
                                                int* __restrict__ rowmax,
                                                int* __restrict__ colmax) {
    __shared__ __align__(16) unsigned char Alds[128 * 128];   // 16 KB
    __shared__ __align__(16) unsigned char Blds[128 * 128];   // 16 KB

    const int bm = blockIdx.x >> 6;
    const int bn = blockIdx.x & 63;
    const int rowb = bm * 128;
    const int colb = bn * 128;

    const int t    = threadIdx.x;
    const int lane = t & 63;
    const int wave = t >> 6;
    const int wm = (wave & 1) * 64;       // wave row offset within tile
    const int wn = (wave >> 1) * 64;      // wave col offset within tile
    const int fr = lane & 15;             // fragment row/col index
    const int fq = lane >> 4;             // quarter (0..3): k-group = fq*8
    const int bof = (fq & 1) * 8;         // byte offset of the 8-fp8 frag within its 16-B chunk

    // staging map: thread t stages LDS row (t>>3), chunk position (t&7); with the
    // XOR swizzle that position holds GLOBAL chunk ((t&7)^(row&7)), 16 B each.
    const int srow = t >> 3;
    const int scol = ((t ^ (t >> 3)) & 7) * 16;   // fp8 elements == bytes

    const unsigned char* Ag = A + (size_t)(rowb + srow) * D_DIM + scol;
    const unsigned char* Bg = B + (size_t)(colb + srow) * D_DIM + scol;

    f32x4 acc[4][4] = {};

    for (int kt = 0; kt < D_DIM; kt += 128) {
        #pragma unroll
        for (int i = 0; i < 4; ++i)
            load16_to_lds(Ag + (size_t)i * 32 * D_DIM + kt,
                          (char*)Alds + i * 4096 + wave * 1024);
        #pragma unroll
        for (int i = 0; i < 4; ++i)
            load16_to_lds(Bg + (size_t)i * 32 * D_DIM + kt,
                          (char*)Blds + i * 4096 + wave * 1024);
        __syncthreads();

        #pragma unroll
        for (int kk = 0; kk < 128; kk += 32) {
            const int cbase = (kk >> 4) + (fq >> 1);   // logical 16-B chunk of this frag
            long av[4], bv[4];
            #pragma unroll
            for (int i = 0; i < 4; ++i) {
                int r = wm + i * 16 + fr;
                av[i] = *(const long*)(Alds + r * 128 + ((cbase ^ (r & 7)) * 16) + bof);
            }
            #pragma unroll
            for (int j = 0; j < 4; ++j) {
                int r = wn + j * 16 + fr;
                bv[j] = *(const long*)(Blds + r * 128 + ((cbase ^ (r & 7)) * 16) + bof);
            }
            #pragma unroll
            for (int i = 0; i < 4; ++i)
                #pragma unroll
                for (int j = 0; j < 4; ++j)
                    acc[i][j] = __builtin_amdgcn_mfma_f32_16x16x32_fp8_fp8(av[i], bv[j], acc[i][j], 0, 0, 0);
        }
        __syncthreads();
    }

    // ---- epilogue: fused max reductions.
    // C/D layout (m89-verified, shape-determined, dtype-independent):
    // col = lane&15 (fr), row = fq*4 + reg.
    const float SH = 2.0f;   // cosine >= -1 -> v+2 > 0 -> int-ordered float bits

    #pragma unroll
    for (int i = 0; i < 4; ++i) {
        #pragma unroll
        for (int r = 0; r < 4; ++r) {
            float m = fmaxf(fmaxf(acc[i][0][r], acc[i][1][r]),
                            fmaxf(acc[i][2][r], acc[i][3][r]));
            m = fmaxf(m, __shfl_xor(m, 1, 64));   // reduce over the 16 lanes sharing fq
            m = fmaxf(m, __shfl_xor(m, 2, 64));
            m = fmaxf(m, __shfl_xor(m, 4, 64));
            m = fmaxf(m, __shfl_xor(m, 8, 64));
            if (fr == 0) {
                int row = rowb + wm + i * 16 + fq * 4 + r;
                atomicMax(&rowmax[row], __float_as_int(m + SH));
            }
        }
    }
    #pragma unroll
    for (int j = 0; j < 4; ++j) {
        float m = -1e30f;
        #pragma unroll
        for (int i = 0; i < 4; ++i)
            #pragma unroll
            for (int r = 0; r < 4; ++r)
                m = fmaxf(m, acc[i][j][r]);
        m = fmaxf(m, __shfl_xor(m, 16, 64));      // reduce over the 4 quarters
        m = fmaxf(m, __shfl_xor(m, 32, 64));
        if (fq == 0) {
            int col = colb + wn + j * 16 + fr;
            atomicMax(&colmax[col], __float_as_int(m + SH));
        }
    }
}

// ---- kernel 3: decode maxes, log-prob, sum. block 0 -> C1 (rowmax), block 1 -> C2 (colmax)
__global__ __launch_bounds__(256) void finalize(const int* __restrict__ rowmax,
                                                const int* __restrict__ colmax,
                                                float* __restrict__ out) {
    const int* src = (blockIdx.x == 0) ? rowmax : colmax;
    int t = threadIdx.x;
    float s = 0.0f;
    for (int i = t; i < NROWS; i += 256) {
        float v = __int_as_float(src[i]) - 2.0f;
        float z = (v - 1.0f) * (1.0f / 0.3f);
        s += -0.5f * z * z + 0.2850342711212634f;   // -(log(0.3)+0.5*log(2*pi))
    }
    #pragma unroll
    for (int off = 32; off; off >>= 1) s += __shfl_xor(s, off, 64);
    __shared__ float wsum[4];
    if ((t & 63) == 0) wsum[t >> 6] = s;
    __syncthreads();
    if (t == 0) out[blockIdx.x] = wsum[0] + wsum[1] + wsum[2] + wsum[3];
}

extern "C" void kernel_launch(void* const* d_in, const int* in_sizes, int n_in,
                              void* d_out, int out_size, void* d_ws, size_t ws_size,
                              hipStream_t stream) {
    const float* ex = (const float*)d_in[0];
    const float* ey = (const float*)d_in[1];
    float* out = (float*)d_out;

    char* ws = (char*)d_ws;
    unsigned char* Aq = (unsigned char*)ws;                                   // 8 MB
    unsigned char* Bq = (unsigned char*)(ws + (size_t)NROWS * D_DIM);         // 8 MB
    int* rowmax = (int*)(ws + (size_t)2 * NROWS * D_DIM);                     // 32 KB
    int* colmax = rowmax + NROWS;                                             // 32 KB

    normalize_rows<<<2 * NROWS, 256, 0, stream>>>(ex, ey, Aq, Bq, rowmax);
    gemm_max<<<64 * 64, 256, 0, stream>>>(Aq, Bq, rowmax, colmax);
    finalize<<<2, 256, 0, stream>>>(rowmax, colmax, out);
}